// Round 10
// baseline (104.506 us; speedup 1.0000x reference)
//
#include <hip/hip_runtime.h>

// PCEN with 10 smoothing rates. x:(B,F,T) f32 -> out:(B,R,F,T) f32
//
// R10 = R7 (dense 1KB loads/stores, dual-chain scan, CACHED stores)
//       + NONTEMPORAL LOADS for x (no L2 allocate; L3 serves re-reads).
// Theory: fill kernel proves cached WRITE-BACK path = 6.9 TB/s. Our cached
// variants cost +~328MB HBM reads; either (i) TCC allocate-fetch RMW or
// (ii) write stream evicts x from L2 -> x re-reads go to HBM. nt loads
// remove (ii): L2 becomes a pure write stream like the fill kernel.
// Decisive: 60-72us => (ii), writes unlocked. ~110us => (i), nt stores
// mandatory and ~91us (R3/R6) is the practical ceiling.
// History: R3 nt=90.8 | R4=100.5 | R5 cached=117 | R6 nt dense=91.5 |
// R7 cached dense=110.7 | R8 LDS-staged nt=108.7 | R9 sgpr+lb=94.0.

typedef float f32x4 __attribute__((ext_vector_type(4)));

constexpr int B_ = 16, F_ = 128, T_ = 4000, R_ = 10;
constexpr float EPS_ = 1e-5f;
constexpr int TPB = 256;            // 4 waves / block
constexpr int WPB = TPB / 64;

__global__ __launch_bounds__(TPB) void pcen_kernel(
    const float* __restrict__ x,
    const float* __restrict__ s_log,
    const float* __restrict__ alpha_log,
    const float* __restrict__ delta_log,
    const float* __restrict__ r_log,
    float* __restrict__ out)
{
    const int wid  = blockIdx.x * WPB + (threadIdx.x >> 6);
    const int lane = threadIdx.x & 63;

    // rate-major: wid = ((b*R + rate)*F + f) -> block's 4 waves write 4
    // consecutive 16KB output rows.
    const int b    = wid / (R_ * F_);
    const int rem  = wid - b * (R_ * F_);
    const int rate = rem / F_;
    const int f    = rem - rate * F_;

    const float s     = __builtin_expf(s_log[rate * F_ + f]);
    const float a     = 1.0f - s;
    const float alpha = __builtin_expf(alpha_log[f]);
    const float delta = __builtin_expf(delta_log[f]);
    const float r     = __builtin_expf(r_log[f]);
    const float delta_r = __builtin_exp2f(r * __builtin_log2f(delta));

    const float a2 = a * a, a3 = a2 * a, a4 = a2 * a2;
    const float a8 = a4 * a4, a16 = a8 * a8, a32 = a16 * a16;
    const float a64 = a32 * a32, a128 = a64 * a64, a256 = a128 * a128;

    // per-lane a^(4*lane), exact product over lane bits
    float pl = 1.0f;
    pl *= (lane & 1)  ? a4   : 1.0f;
    pl *= (lane & 2)  ? a8   : 1.0f;
    pl *= (lane & 4)  ? a16  : 1.0f;
    pl *= (lane & 8)  ? a32  : 1.0f;
    pl *= (lane & 16) ? a64  : 1.0f;
    pl *= (lane & 32) ? a128 : 1.0f;

    const float* xrow = x   + (size_t)(b * F_ + f) * T_;
    float*       orow = out + (size_t)((b * R_ + rate) * F_ + f) * T_;

    float carry = __builtin_nontemporal_load(xrow);  // y_{-1} := x_0

    auto pcen1 = [&](float xv, float m) -> float {
        const float sm = __builtin_exp2f(-alpha * __builtin_log2f(EPS_ + m));
        return __builtin_exp2f(r * __builtin_log2f(fmaf(xv, sm, delta))) - delta_r;
    };

    for (int t0 = 0; t0 < T_; t0 += 512) {
        const int tA = t0 + lane * 4;
        const int tB = tA + 256;
        const bool actA = (tA < T_);
        const bool actB = (tB < T_);
        f32x4 vA = {0.f, 0.f, 0.f, 0.f};
        f32x4 vB = {0.f, 0.f, 0.f, 0.f};
        if (actA) vA = __builtin_nontemporal_load(
                           reinterpret_cast<const f32x4*>(xrow + tA));
        if (actB) vB = __builtin_nontemporal_load(
                           reinterpret_cast<const f32x4*>(xrow + tB));

        // local zero-init scans (independent)
        const float lA0 = s * vA.x;
        const float lA1 = fmaf(a, lA0, s * vA.y);
        const float lA2 = fmaf(a, lA1, s * vA.z);
        const float lA3 = fmaf(a, lA2, s * vA.w);
        const float lB0 = s * vB.x;
        const float lB1 = fmaf(a, lB0, s * vB.y);
        const float lB2 = fmaf(a, lB1, s * vB.z);
        const float lB3 = fmaf(a, lB2, s * vB.w);

        float YA = lA3;
        if (lane == 0) YA = fmaf(a4, carry, YA);   // fold prev-chunk carry
        float YB = lB3;                             // zero-init chain

        // two interleaved Hillis-Steele scans, segment multiplier a^4
        float uA, uB;
        uA = __shfl_up(YA, 1);  uB = __shfl_up(YB, 1);
        if (lane >= 1)  { YA = fmaf(a4,   uA, YA); YB = fmaf(a4,   uB, YB); }
        uA = __shfl_up(YA, 2);  uB = __shfl_up(YB, 2);
        if (lane >= 2)  { YA = fmaf(a8,   uA, YA); YB = fmaf(a8,   uB, YB); }
        uA = __shfl_up(YA, 4);  uB = __shfl_up(YB, 4);
        if (lane >= 4)  { YA = fmaf(a16,  uA, YA); YB = fmaf(a16,  uB, YB); }
        uA = __shfl_up(YA, 8);  uB = __shfl_up(YB, 8);
        if (lane >= 8)  { YA = fmaf(a32,  uA, YA); YB = fmaf(a32,  uB, YB); }
        uA = __shfl_up(YA, 16); uB = __shfl_up(YB, 16);
        if (lane >= 16) { YA = fmaf(a64,  uA, YA); YB = fmaf(a64,  uB, YB); }
        uA = __shfl_up(YA, 32); uB = __shfl_up(YB, 32);
        if (lane >= 32) { YA = fmaf(a128, uA, YA); YB = fmaf(a128, uB, YB); }

        float yinA = __shfl_up(YA, 1);
        if (lane == 0) yinA = carry;
        float yinB = __shfl_up(YB, 1);
        if (lane == 0) yinB = 0.0f;
        const float exitA = __shfl(YA, 63);
        yinB = fmaf(pl, exitA, yinB);              // link chain B to chain A
        carry = fmaf(a256, exitA, __shfl(YB, 63)); // chunk-exit state

        if (actA) {
            const float mA0 = fmaf(a,  yinA, lA0);
            const float mA1 = fmaf(a2, yinA, lA1);
            const float mA2 = fmaf(a3, yinA, lA2);
            const float mA3 = fmaf(a4, yinA, lA3);
            f32x4 o;
            o.x = pcen1(vA.x, mA0);
            o.y = pcen1(vA.y, mA1);
            o.z = pcen1(vA.z, mA2);
            o.w = pcen1(vA.w, mA3);
            *reinterpret_cast<f32x4*>(orow + tA) = o;   // cached write-back
        }
        if (actB) {
            const float mB0 = fmaf(a,  yinB, lB0);
            const float mB1 = fmaf(a2, yinB, lB1);
            const float mB2 = fmaf(a3, yinB, lB2);
            const float mB3 = fmaf(a4, yinB, lB3);
            f32x4 o;
            o.x = pcen1(vB.x, mB0);
            o.y = pcen1(vB.y, mB1);
            o.z = pcen1(vB.z, mB2);
            o.w = pcen1(vB.w, mB3);
            *reinterpret_cast<f32x4*>(orow + tB) = o;
        }
    }
}

extern "C" void kernel_launch(void* const* d_in, const int* in_sizes, int n_in,
                              void* d_out, int out_size, void* d_ws, size_t ws_size,
                              hipStream_t stream) {
    const float* x         = (const float*)d_in[0];
    const float* s_log     = (const float*)d_in[1];
    const float* alpha_log = (const float*)d_in[2];
    const float* delta_log = (const float*)d_in[3];
    const float* r_log     = (const float*)d_in[4];
    float* out = (float*)d_out;

    const int n_waves = B_ * R_ * F_;          // 20480
    const int blocks  = n_waves / WPB;         // 5120
    pcen_kernel<<<blocks, TPB, 0, stream>>>(x, s_log, alpha_log, delta_log, r_log, out);
}

// Round 11
// 99.044 us; speedup vs baseline: 1.0551x; 1.0551x over previous
//
#include <hip/hip_runtime.h>

// PCEN with 10 smoothing rates. x:(B,F,T) f32 -> out:(B,R,F,T) f32
//
// R11: BLOCK-OWNS-ROW. One 256-thread block = one (b,rate,f) row of 4000.
//   Wave w owns segment [w*1024, +1024) as 4 chains of 256 (R6 machinery:
//   per-lane 4-elem local scan, 6-step shuffle scan, analytic chain link
//   via pl=a^(4*lane)). Waves linked by ONE LDS exchange (single barrier):
//   in_w = a^1024*in_{w-1} + Eloc_{w-1}, in_0 = x_0.
//   Result: the block stores the WHOLE 16KB row as one dense burst, and
//   blocks retire in dispatch order -> near-sequential DRAM write stream
//   (the fill kernel's pattern, 6.9 TB/s). This is the last untested
//   variable: all R3-R10 variants interleaved 20480 fine-grained row
//   streams (time-scattered writes), nt/cached/density/staging/occupancy
//   all plateaued at ~91us ~= 4 TB/s.
// History: R3 nt=90.8 | R4=100.5 | R5 cached=117 | R6 nt dense=91.5 |
// R7 cached dense=110.7 | R8 LDS nt=108.7 | R9 sgpr+lb=94.0 | R10 ntload
// +cached=104.5.

typedef float f32x4 __attribute__((ext_vector_type(4)));

constexpr int B_ = 16, F_ = 128, T_ = 4000, R_ = 10;
constexpr float EPS_ = 1e-5f;
constexpr int TPB = 256;

__global__ __launch_bounds__(TPB) void pcen_kernel(
    const float* __restrict__ x,
    const float* __restrict__ s_log,
    const float* __restrict__ alpha_log,
    const float* __restrict__ delta_log,
    const float* __restrict__ r_log,
    float* __restrict__ out)
{
    __shared__ float eloc[4];

    const int bid  = blockIdx.x;            // rate-major: consecutive blocks =
    const int b    = bid / (R_ * F_);       // consecutive output rows
    const int rem  = bid - b * (R_ * F_);
    const int rate = rem / F_;
    const int f    = rem - rate * F_;

    const int wv   = threadIdx.x >> 6;
    const int lane = threadIdx.x & 63;

    const float s     = __builtin_expf(s_log[rate * F_ + f]);
    const float a     = 1.0f - s;
    const float alpha = __builtin_expf(alpha_log[f]);
    const float delta = __builtin_expf(delta_log[f]);
    const float r     = __builtin_expf(r_log[f]);
    const float delta_r = __builtin_exp2f(r * __builtin_log2f(delta));

    const float a2 = a * a, a3 = a2 * a, a4 = a2 * a2;
    const float a8 = a4 * a4, a16 = a8 * a8, a32 = a16 * a16;
    const float a64 = a32 * a32, a128 = a64 * a64, a256 = a128 * a128;
    const float a512 = a256 * a256, a1024 = a512 * a512;

    // per-lane a^(4*lane)
    float pl = 1.0f;
    pl *= (lane & 1)  ? a4   : 1.0f;
    pl *= (lane & 2)  ? a8   : 1.0f;
    pl *= (lane & 4)  ? a16  : 1.0f;
    pl *= (lane & 8)  ? a32  : 1.0f;
    pl *= (lane & 16) ? a64  : 1.0f;
    pl *= (lane & 32) ? a128 : 1.0f;

    const float* xrow = x   + (size_t)(b * F_ + f) * T_;
    float*       orow = out + (size_t)((b * R_ + rate) * F_ + f) * T_;

    const int base = wv * 1024;

    // ---- load 4 chains (each: dense 1KB per instruction) ----
    f32x4 v[4];
    bool  act[4];
#pragma unroll
    for (int c = 0; c < 4; ++c) {
        const int t = base + c * 256 + lane * 4;
        act[c] = (t < T_);                 // only wave3/chain3 partial
        f32x4 z = {0.f, 0.f, 0.f, 0.f};
        v[c] = act[c] ? *reinterpret_cast<const f32x4*>(xrow + t) : z;
    }

    // ---- local 4-elem zero-init scans ----
    float l[4][4];
#pragma unroll
    for (int c = 0; c < 4; ++c) {
        l[c][0] = s * v[c].x;
        l[c][1] = fmaf(a, l[c][0], s * v[c].y);
        l[c][2] = fmaf(a, l[c][1], s * v[c].z);
        l[c][3] = fmaf(a, l[c][2], s * v[c].w);
    }

    // ---- 4 interleaved Hillis-Steele wave scans (zero init) ----
    float Y[4] = {l[0][3], l[1][3], l[2][3], l[3][3]};
    const float mult[6] = {a4, a8, a16, a32, a64, a128};
#pragma unroll
    for (int i = 0; i < 6; ++i) {
        const int d = 1 << i;
        float up[4];
#pragma unroll
        for (int c = 0; c < 4; ++c) up[c] = __shfl_up(Y[c], d);
        if (lane >= d) {
#pragma unroll
            for (int c = 0; c < 4; ++c) Y[c] = fmaf(mult[i], up[c], Y[c]);
        }
    }

    // ---- chain exits, wave-local exit, LDS exchange ----
    float X[4];
#pragma unroll
    for (int c = 0; c < 4; ++c) X[c] = __shfl(Y[c], 63);
    const float El = fmaf(a256, fmaf(a256, fmaf(a256, X[0], X[1]), X[2]), X[3]);
    if (lane == 0) eloc[wv] = El;
    __syncthreads();

    // carry into this wave's segment: in_0 = x_0 (y_{-1}=x_0 trick, a+s=1)
    float in = xrow[0];
#pragma unroll
    for (int vv = 0; vv < 3; ++vv)
        if (vv < wv) in = fmaf(a1024, in, eloc[vv]);

    // chain carry-ins
    float cin[4];
    cin[0] = in;
    cin[1] = fmaf(a256, cin[0], X[0]);
    cin[2] = fmaf(a256, cin[1], X[1]);
    cin[3] = fmaf(a256, cin[2], X[2]);

    auto pcen1 = [&](float xv, float m) -> float {
        const float sm = __builtin_exp2f(-alpha * __builtin_log2f(EPS_ + m));
        return __builtin_exp2f(r * __builtin_log2f(fmaf(xv, sm, delta))) - delta_r;
    };

    // ---- fixup + epilogue + dense nt stores (whole row in one burst) ----
#pragma unroll
    for (int c = 0; c < 4; ++c) {
        float u = __shfl_up(Y[c], 1);
        float yy = (lane == 0) ? 0.0f : u;
        const float yin = fmaf(pl, cin[c], yy);
        if (act[c]) {
            const float m0 = fmaf(a,  yin, l[c][0]);
            const float m1 = fmaf(a2, yin, l[c][1]);
            const float m2 = fmaf(a3, yin, l[c][2]);
            const float m3 = fmaf(a4, yin, l[c][3]);
            f32x4 o;
            o.x = pcen1(v[c].x, m0);
            o.y = pcen1(v[c].y, m1);
            o.z = pcen1(v[c].z, m2);
            o.w = pcen1(v[c].w, m3);
            const int t = base + c * 256 + lane * 4;
            __builtin_nontemporal_store(o, reinterpret_cast<f32x4*>(orow + t));
        }
    }
}

extern "C" void kernel_launch(void* const* d_in, const int* in_sizes, int n_in,
                              void* d_out, int out_size, void* d_ws, size_t ws_size,
                              hipStream_t stream) {
    const float* x         = (const float*)d_in[0];
    const float* s_log     = (const float*)d_in[1];
    const float* alpha_log = (const float*)d_in[2];
    const float* delta_log = (const float*)d_in[3];
    const float* r_log     = (const float*)d_in[4];
    float* out = (float*)d_out;

    const int blocks = B_ * R_ * F_;           // 20480: one block per row
    pcen_kernel<<<blocks, TPB, 0, stream>>>(x, s_log, alpha_log, delta_log, r_log, out);
}